// Round 1
// baseline (687.153 us; speedup 1.0000x reference)
//
#include <hip/hip_runtime.h>

// ---------------------------------------------------------------------------
// DualGCN: two GCN branches + merge.
//   branch a: h=relu(x@Wa0.T+ba0); h=relu(spmm_a(h)@Wa1.T+ba1); x_a=spmm_a(h)
//   branch b: g0=relu(x@Wb0.T+bb0); g1=relu(spmm_b(g0)@Wb1.T+bb1); g2=spmm_b(g1)
//             x_b=relu(concat(g0,g1,g2)@Wm.T+bm)
//   out = concat(x_a,x_b)@Wo.T + bo
// All fp32. N=50000, E=800000, H=128, OUT=64.
// ---------------------------------------------------------------------------

// rowptr[i] = first edge index e with row[e] >= i  (row is sorted)
__global__ __launch_bounds__(256) void build_rowptr_kernel(
    const int* __restrict__ row, int E, int n, int* __restrict__ rowptr)
{
  int i = blockIdx.x * blockDim.x + threadIdx.x;
  if (i > n) return;
  int lo = 0, hi = E;
  while (lo < hi) {
    int mid = (lo + hi) >> 1;
    if (row[mid] < i) lo = mid + 1; else hi = mid;
  }
  rowptr[i] = lo;
}

// Y[r,:] = sum_{e in [rowptr[r],rowptr[r+1])} val[e] * X[col[e],:]
// One 32-lane group per row; lane owns a float4 of the 128-wide feature dim.
__global__ __launch_bounds__(256) void spmm_kernel(
    const int* __restrict__ rowptr, const int* __restrict__ col,
    const float* __restrict__ val, const float* __restrict__ X,
    float* __restrict__ Y, int n)
{
  int g = blockIdx.x * 8 + (threadIdx.x >> 5);
  int lane = threadIdx.x & 31;
  if (g >= n) return;
  int e0 = rowptr[g], e1 = rowptr[g + 1];
  float ax = 0.f, ay = 0.f, az = 0.f, aw = 0.f;
  for (int e = e0; e < e1; ++e) {
    int c = col[e];
    float v = val[e];
    const float4 xv = *(const float4*)(X + (size_t)c * 128 + lane * 4);
    ax = fmaf(v, xv.x, ax);
    ay = fmaf(v, xv.y, ay);
    az = fmaf(v, xv.z, az);
    aw = fmaf(v, xv.w, aw);
  }
  float4 o; o.x = ax; o.y = ay; o.z = az; o.w = aw;
  *(float4*)(Y + (size_t)g * 128 + lane * 4) = o;
}

// Y[i,j] = (relu?)( sum_k X[i,k] * W[j,k] + b[j] )
// X is given as up to 3 slab pointers, one per 128-col chunk of K (free concat).
// All X slabs have row stride 128. Y has row stride HOUT.
// Block tile: 64 rows x HOUT cols; KC=64 K-chunks staged in LDS; 4xTN reg tile.
template <int K, int HOUT, bool RELU>
__global__ __launch_bounds__(256) void linear_kernel(
    const float* __restrict__ X0, const float* __restrict__ X1,
    const float* __restrict__ X2,
    const float* __restrict__ W,  // [HOUT, K] row-major
    const float* __restrict__ b,
    float* __restrict__ Y, int n)
{
  constexpr int KC = 64;
  constexpr int TN = (HOUT >= 128) ? 8 : 4;
  constexpr int TX = HOUT / TN;   // 16
  constexpr int TY = 256 / TX;    // 16
  constexpr int TM = 4;
  constexpr int BM = TY * TM;     // 64 rows per block
  constexpr int LDSS = KC + 4;    // pad: +4 floats keeps b128 reads <=2-way banked

  __shared__ float Xs[BM * LDSS];
  __shared__ float Ws[HOUT * LDSS];

  const int tid = threadIdx.x;
  const int tx = tid % TX;
  const int ty = tid / TX;
  const int row0 = blockIdx.x * BM;

  float acc[TM][TN];
#pragma unroll
  for (int i = 0; i < TM; ++i)
#pragma unroll
    for (int j = 0; j < TN; ++j) acc[i][j] = 0.f;

  for (int k0 = 0; k0 < K; k0 += KC) {
    const float* Xp = (k0 < 128) ? X0 : (k0 < 256) ? X1 : X2;
    const int koff = k0 & 127;
    // stage X tile (BM x KC)
    for (int s = tid; s < BM * (KC / 4); s += 256) {
      int r = s / (KC / 4), q = s % (KC / 4);
      int grow = row0 + r;
      float4 v = make_float4(0.f, 0.f, 0.f, 0.f);
      if (grow < n) v = *(const float4*)(Xp + (size_t)grow * 128 + koff + q * 4);
      *(float4*)(Xs + r * LDSS + q * 4) = v;
    }
    // stage W tile (HOUT x KC)
    for (int s = tid; s < HOUT * (KC / 4); s += 256) {
      int r = s / (KC / 4), q = s % (KC / 4);
      *(float4*)(Ws + r * LDSS + q * 4) =
          *(const float4*)(W + (size_t)r * K + k0 + q * 4);
    }
    __syncthreads();
#pragma unroll
    for (int kk = 0; kk < KC; kk += 4) {
      float4 xa[TM], wb[TN];
#pragma unroll
      for (int i = 0; i < TM; ++i)
        xa[i] = *(const float4*)(Xs + (ty + TY * i) * LDSS + kk);
#pragma unroll
      for (int j = 0; j < TN; ++j)
        wb[j] = *(const float4*)(Ws + (tx + TX * j) * LDSS + kk);
#pragma unroll
      for (int i = 0; i < TM; ++i)
#pragma unroll
        for (int j = 0; j < TN; ++j) {
          acc[i][j] = fmaf(xa[i].x, wb[j].x, acc[i][j]);
          acc[i][j] = fmaf(xa[i].y, wb[j].y, acc[i][j]);
          acc[i][j] = fmaf(xa[i].z, wb[j].z, acc[i][j]);
          acc[i][j] = fmaf(xa[i].w, wb[j].w, acc[i][j]);
        }
    }
    __syncthreads();
  }
#pragma unroll
  for (int i = 0; i < TM; ++i) {
    int grow = row0 + ty + TY * i;
    if (grow >= n) continue;
#pragma unroll
    for (int j = 0; j < TN; ++j) {
      int colj = tx + TX * j;
      float v = acc[i][j] + b[colj];
      if (RELU) v = fmaxf(v, 0.f);
      Y[(size_t)grow * HOUT + colj] = v;
    }
  }
}

extern "C" void kernel_launch(void* const* d_in, const int* in_sizes, int n_in,
                              void* d_out, int out_size, void* d_ws, size_t ws_size,
                              hipStream_t stream)
{
  const float* x     = (const float*)d_in[0];
  const int*   row_a = (const int*)d_in[1];
  const int*   col_a = (const int*)d_in[2];
  const float* val_a = (const float*)d_in[3];
  const int*   row_b = (const int*)d_in[4];
  const int*   col_b = (const int*)d_in[5];
  const float* val_b = (const float*)d_in[6];
  const float* Wa0 = (const float*)d_in[7];  const float* ba0 = (const float*)d_in[8];
  const float* Wa1 = (const float*)d_in[9];  const float* ba1 = (const float*)d_in[10];
  const float* Wb0 = (const float*)d_in[11]; const float* bb0 = (const float*)d_in[12];
  const float* Wb1 = (const float*)d_in[13]; const float* bb1 = (const float*)d_in[14];
  const float* Wm  = (const float*)d_in[15]; const float* bm  = (const float*)d_in[16];
  const float* Wo  = (const float*)d_in[17]; const float* bo  = (const float*)d_in[18];
  float* out = (float*)d_out;

  const int n = in_sizes[0] / 128;   // 50000
  const int E = in_sizes[1];         // 800000

  // workspace: 2 rowptrs + 5 [n,128] fp32 slabs (aliased across stages)
  char* ws = (char*)d_ws;
  size_t off = 0;
  auto alloc = [&](size_t bytes) {
    void* p = ws + off;
    off = (off + bytes + 255) & ~(size_t)255;
    return p;
  };
  int*   rpa = (int*)alloc((size_t)(n + 1) * sizeof(int));
  int*   rpb = (int*)alloc((size_t)(n + 1) * sizeof(int));
  float* A   = (float*)alloc((size_t)n * 128 * sizeof(float)); // h1/h2, later x_b
  float* B   = (float*)alloc((size_t)n * 128 * sizeof(float)); // spmm temp, later g2
  float* C   = (float*)alloc((size_t)n * 128 * sizeof(float)); // g0
  float* D   = (float*)alloc((size_t)n * 128 * sizeof(float)); // g1
  float* Eo  = (float*)alloc((size_t)n * 128 * sizeof(float)); // x_a

  dim3 blk(256);
  dim3 g_rp((n + 1 + 255) / 256);
  dim3 g_lin((n + 63) / 64);
  dim3 g_sp((n + 7) / 8);

  build_rowptr_kernel<<<g_rp, blk, 0, stream>>>(row_a, E, n, rpa);
  build_rowptr_kernel<<<g_rp, blk, 0, stream>>>(row_b, E, n, rpb);

  // branch a
  linear_kernel<128, 128, true><<<g_lin, blk, 0, stream>>>(x, nullptr, nullptr, Wa0, ba0, A, n);
  spmm_kernel<<<g_sp, blk, 0, stream>>>(rpa, col_a, val_a, A, B, n);
  linear_kernel<128, 128, true><<<g_lin, blk, 0, stream>>>(B, nullptr, nullptr, Wa1, ba1, A, n);
  spmm_kernel<<<g_sp, blk, 0, stream>>>(rpa, col_a, val_a, A, Eo, n);   // x_a

  // branch b
  linear_kernel<128, 128, true><<<g_lin, blk, 0, stream>>>(x, nullptr, nullptr, Wb0, bb0, C, n); // g0
  spmm_kernel<<<g_sp, blk, 0, stream>>>(rpb, col_b, val_b, C, B, n);
  linear_kernel<128, 128, true><<<g_lin, blk, 0, stream>>>(B, nullptr, nullptr, Wb1, bb1, D, n); // g1
  spmm_kernel<<<g_sp, blk, 0, stream>>>(rpb, col_b, val_b, D, B, n);    // g2
  // x_b = relu(concat(g0,g1,g2) @ Wm.T + bm)
  linear_kernel<384, 128, true><<<g_lin, blk, 0, stream>>>(C, D, B, Wm, bm, A, n);

  // out = concat(x_a, x_b) @ Wo.T + bo
  linear_kernel<256, 64, false><<<g_lin, blk, 0, stream>>>(Eo, A, nullptr, Wo, bo, out, n);
}

// Round 2
// 417.016 us; speedup vs baseline: 1.6478x; 1.6478x over previous
//
#include <hip/hip_runtime.h>

// ---------------------------------------------------------------------------
// DualGCN, bf16-MFMA version.
//   All [N,128] intermediate slabs stored as bf16 (ushort). GEMMs via
//   v_mfma_f32_16x16x32_bf16 with fp32 accumulation; SpMM gathers bf16 rows
//   and accumulates fp32. Weights converted fp32->bf16 on device each call.
// N=50000, E=800000, H=128, OUT=64.
// ---------------------------------------------------------------------------

typedef short short8 __attribute__((ext_vector_type(8)));
typedef float floatx4 __attribute__((ext_vector_type(4)));

__device__ inline unsigned short f2bf(float f) {
  unsigned u = __builtin_bit_cast(unsigned, f);
  u += 0x7fffu + ((u >> 16) & 1u);      // round-to-nearest-even
  return (unsigned short)(u >> 16);
}
__device__ inline unsigned pack2(float a, float b) {
  return (unsigned)f2bf(a) | ((unsigned)f2bf(b) << 16);
}
__device__ inline float bf_lo(unsigned w) {
  return __builtin_bit_cast(float, w << 16);
}
__device__ inline float bf_hi(unsigned w) {
  return __builtin_bit_cast(float, w & 0xffff0000u);
}

// rowptr[i] = first edge index e with row[e] >= i  (row is sorted)
__global__ __launch_bounds__(256) void build_rowptr_kernel(
    const int* __restrict__ row, int E, int n, int* __restrict__ rowptr)
{
  int i = blockIdx.x * blockDim.x + threadIdx.x;
  if (i > n) return;
  int lo = 0, hi = E;
  while (lo < hi) {
    int mid = (lo + hi) >> 1;
    if (row[mid] < i) lo = mid + 1; else hi = mid;
  }
  rowptr[i] = lo;
}

// fp32 -> bf16, 4 elements/thread
__global__ __launch_bounds__(256) void convert_x_kernel(
    const float* __restrict__ in, unsigned short* __restrict__ out, int n4)
{
  int i = blockIdx.x * 256 + threadIdx.x;
  if (i >= n4) return;
  float4 v = ((const float4*)in)[i];
  uint2 p; p.x = pack2(v.x, v.y); p.y = pack2(v.z, v.w);
  ((uint2*)out)[i] = p;
}

// all six weight matrices -> one concatenated bf16 buffer
// offsets: Wa0 0, Wa1 16384, Wb0 32768, Wb1 49152, Wm 65536 (49152), Wo 114688 (16384)
__global__ __launch_bounds__(256) void convert_w_kernel(
    const float* __restrict__ Wa0, const float* __restrict__ Wa1,
    const float* __restrict__ Wb0, const float* __restrict__ Wb1,
    const float* __restrict__ Wm,  const float* __restrict__ Wo,
    unsigned short* __restrict__ out)
{
  int i = blockIdx.x * 256 + threadIdx.x;
  if (i >= 131072) return;
  float v;
  if      (i < 16384)  v = Wa0[i];
  else if (i < 32768)  v = Wa1[i - 16384];
  else if (i < 49152)  v = Wb0[i - 32768];
  else if (i < 65536)  v = Wb1[i - 49152];
  else if (i < 114688) v = Wm[i - 65536];
  else                 v = Wo[i - 114688];
  out[i] = f2bf(v);
}

// Y[r,:] = sum_e val[e] * X[col[e],:]   (bf16 in, fp32 accum, bf16 out)
// 32-lane group per row; lane owns 4 bf16 (8 B) of the 128-wide feature dim.
__global__ __launch_bounds__(256) void spmm_bf16_kernel(
    const int* __restrict__ rowptr, const int* __restrict__ col,
    const float* __restrict__ val, const unsigned short* __restrict__ X,
    unsigned short* __restrict__ Y, int n)
{
  int g = blockIdx.x * 8 + (threadIdx.x >> 5);
  int lane = threadIdx.x & 31;
  if (g >= n) return;
  int e0 = rowptr[g], e1 = rowptr[g + 1];
  float a0 = 0.f, a1 = 0.f, a2 = 0.f, a3 = 0.f;
  for (int e = e0; e < e1; ++e) {
    int c = col[e];
    float v = val[e];
    uint2 w = *(const uint2*)(X + (size_t)c * 128 + lane * 4);
    a0 = fmaf(v, bf_lo(w.x), a0);
    a1 = fmaf(v, bf_hi(w.x), a1);
    a2 = fmaf(v, bf_lo(w.y), a2);
    a3 = fmaf(v, bf_hi(w.y), a3);
  }
  uint2 o; o.x = pack2(a0, a1); o.y = pack2(a2, a3);
  *(uint2*)(Y + (size_t)g * 128 + lane * 4) = o;
}

// Y = (relu?)(X @ W.T + b), X bf16 (up to 3 slabs of 128 cols each = free
// concat), W bf16 [HOUT,K], Y bf16 or fp32.
// Block: 256 thr = 4 waves in 2x2 (wm,wn); tile 128 rows x HOUT cols.
// MFMA operand swap (a=W, b=X) -> lane's 4 acc regs are 4 consecutive output
// COLS -> packed 8B/16B stores.
template <int K, int HOUT, bool RELU, bool OUTBF>
__global__ __launch_bounds__(256, 2) void mfma_linear_kernel(
    const unsigned short* __restrict__ X0, const unsigned short* __restrict__ X1,
    const unsigned short* __restrict__ X2, const unsigned short* __restrict__ W,
    const float* __restrict__ b, void* __restrict__ Yv, int n)
{
  constexpr int LDX = 136;        // padded LDS row stride (bf16 units): 2-way banked only
  constexpr int NT = HOUT / 32;   // n-tiles per wave (4 for H=128, 2 for H=64)
  constexpr int MT = 4;           // m-tiles per wave (64 rows)

  __shared__ unsigned short Xs[128 * LDX];
  __shared__ unsigned short Ws[HOUT * LDX];

  const int tid  = threadIdx.x;
  const int lane = tid & 63;
  const int wave = tid >> 6;
  const int wm   = wave >> 1;     // 0..1 : row half
  const int wn   = wave & 1;      // 0..1 : col half
  const int l15  = lane & 15;
  const int quad = lane >> 4;
  const int row0 = blockIdx.x * 128;

  const int c8   = (tid & 15) * 8;  // staging: 8 bf16 = 16 B per thread
  const int rloc = tid >> 4;        // staging: 16 threads per row

  floatx4 acc[MT][NT];
#pragma unroll
  for (int i = 0; i < MT; ++i)
#pragma unroll
    for (int j = 0; j < NT; ++j) acc[i][j] = (floatx4){0.f, 0.f, 0.f, 0.f};

  for (int kc = 0; kc < K; kc += 128) {
    const unsigned short* Xp = (kc == 0) ? X0 : (kc == 128) ? X1 : X2;
    // stage X tile: 128 rows x 128 bf16
#pragma unroll
    for (int p = 0; p < 8; ++p) {
      int r = p * 16 + rloc;
      int gr = row0 + r;
      uint4 v = make_uint4(0u, 0u, 0u, 0u);
      if (gr < n) v = *(const uint4*)(Xp + (size_t)gr * 128 + c8);
      *(uint4*)(Xs + r * LDX + c8) = v;
    }
    // stage W tile: HOUT rows x 128 bf16 (row stride K in global)
#pragma unroll
    for (int p = 0; p < HOUT / 16; ++p) {
      int r = p * 16 + rloc;
      uint4 v = *(const uint4*)(W + (size_t)r * K + kc + c8);
      *(uint4*)(Ws + r * LDX + c8) = v;
    }
    __syncthreads();
#pragma unroll
    for (int k0 = 0; k0 < 128; k0 += 32) {
      const int ko = k0 + quad * 8;
      short8 aW[NT], bX[MT];
#pragma unroll
      for (int j = 0; j < NT; ++j)
        aW[j] = *(const short8*)(Ws + (wn * (16 * NT) + j * 16 + l15) * LDX + ko);
#pragma unroll
      for (int i = 0; i < MT; ++i)
        bX[i] = *(const short8*)(Xs + (wm * 64 + i * 16 + l15) * LDX + ko);
#pragma unroll
      for (int i = 0; i < MT; ++i)
#pragma unroll
        for (int j = 0; j < NT; ++j)
          acc[i][j] = __builtin_amdgcn_mfma_f32_16x16x32_bf16(
              aW[j], bX[i], acc[i][j], 0, 0, 0);
    }
    __syncthreads();
  }

  // epilogue: D[m][n] -> out row = X-row (lane&15), cols = quad*4 + reg (4 consecutive)
#pragma unroll
  for (int i = 0; i < MT; ++i) {
    int r = row0 + wm * 64 + i * 16 + l15;
    if (r >= n) continue;
#pragma unroll
    for (int j = 0; j < NT; ++j) {
      int c0 = wn * (16 * NT) + j * 16 + quad * 4;
      float4 bb = *(const float4*)(b + c0);
      float v0 = acc[i][j][0] + bb.x;
      float v1 = acc[i][j][1] + bb.y;
      float v2 = acc[i][j][2] + bb.z;
      float v3 = acc[i][j][3] + bb.w;
      if (RELU) {
        v0 = fmaxf(v0, 0.f); v1 = fmaxf(v1, 0.f);
        v2 = fmaxf(v2, 0.f); v3 = fmaxf(v3, 0.f);
      }
      if (OUTBF) {
        uint2 o; o.x = pack2(v0, v1); o.y = pack2(v2, v3);
        *(uint2*)((unsigned short*)Yv + (size_t)r * HOUT + c0) = o;
      } else {
        float4 o; o.x = v0; o.y = v1; o.z = v2; o.w = v3;
        *(float4*)((float*)Yv + (size_t)r * HOUT + c0) = o;
      }
    }
  }
}

extern "C" void kernel_launch(void* const* d_in, const int* in_sizes, int n_in,
                              void* d_out, int out_size, void* d_ws, size_t ws_size,
                              hipStream_t stream)
{
  const float* x     = (const float*)d_in[0];
  const int*   row_a = (const int*)d_in[1];
  const int*   col_a = (const int*)d_in[2];
  const float* val_a = (const float*)d_in[3];
  const int*   row_b = (const int*)d_in[4];
  const int*   col_b = (const int*)d_in[5];
  const float* val_b = (const float*)d_in[6];
  const float* Wa0 = (const float*)d_in[7];  const float* ba0 = (const float*)d_in[8];
  const float* Wa1 = (const float*)d_in[9];  const float* ba1 = (const float*)d_in[10];
  const float* Wb0 = (const float*)d_in[11]; const float* bb0 = (const float*)d_in[12];
  const float* Wb1 = (const float*)d_in[13]; const float* bb1 = (const float*)d_in[14];
  const float* Wm  = (const float*)d_in[15]; const float* bm  = (const float*)d_in[16];
  const float* Wo  = (const float*)d_in[17]; const float* bo  = (const float*)d_in[18];
  float* out = (float*)d_out;

  const int n = in_sizes[0] / 128;   // 50000
  const int E = in_sizes[1];         // 800000

  char* ws = (char*)d_ws;
  size_t off = 0;
  auto alloc = [&](size_t bytes) {
    void* p = ws + off;
    off = (off + bytes + 255) & ~(size_t)255;
    return p;
  };
  int* rpa = (int*)alloc((size_t)(n + 1) * sizeof(int));
  int* rpb = (int*)alloc((size_t)(n + 1) * sizeof(int));
  unsigned short* Wcat = (unsigned short*)alloc(131072 * sizeof(unsigned short));
  const size_t slab = (size_t)n * 128 * sizeof(unsigned short);
  unsigned short* xb = (unsigned short*)alloc(slab);
  unsigned short* A  = (unsigned short*)alloc(slab);
  unsigned short* B  = (unsigned short*)alloc(slab);
  unsigned short* C  = (unsigned short*)alloc(slab);
  unsigned short* D  = (unsigned short*)alloc(slab);
  unsigned short* Eo = (unsigned short*)alloc(slab);

  const unsigned short* Wa0b = Wcat;
  const unsigned short* Wa1b = Wcat + 16384;
  const unsigned short* Wb0b = Wcat + 32768;
  const unsigned short* Wb1b = Wcat + 49152;
  const unsigned short* Wmb  = Wcat + 65536;
  const unsigned short* Wob  = Wcat + 114688;

  dim3 blk(256);
  dim3 g_rp((n + 1 + 255) / 256);
  dim3 g_cx((n * 128 / 4 + 255) / 256);
  dim3 g_cw((131072 + 255) / 256);
  dim3 g_lin((n + 127) / 128);
  dim3 g_sp((n + 7) / 8);

  build_rowptr_kernel<<<g_rp, blk, 0, stream>>>(row_a, E, n, rpa);
  build_rowptr_kernel<<<g_rp, blk, 0, stream>>>(row_b, E, n, rpb);
  convert_x_kernel<<<g_cx, blk, 0, stream>>>(x, xb, n * 128 / 4);
  convert_w_kernel<<<g_cw, blk, 0, stream>>>(Wa0, Wa1, Wb0, Wb1, Wm, Wo, Wcat);

  // branch a
  mfma_linear_kernel<128, 128, true, true><<<g_lin, blk, 0, stream>>>(
      xb, nullptr, nullptr, Wa0b, ba0, A, n);
  spmm_bf16_kernel<<<g_sp, blk, 0, stream>>>(rpa, col_a, val_a, A, B, n);
  mfma_linear_kernel<128, 128, true, true><<<g_lin, blk, 0, stream>>>(
      B, nullptr, nullptr, Wa1b, ba1, A, n);
  spmm_bf16_kernel<<<g_sp, blk, 0, stream>>>(rpa, col_a, val_a, A, Eo, n);  // x_a

  // branch b
  mfma_linear_kernel<128, 128, true, true><<<g_lin, blk, 0, stream>>>(
      xb, nullptr, nullptr, Wb0b, bb0, C, n);                               // g0
  spmm_bf16_kernel<<<g_sp, blk, 0, stream>>>(rpb, col_b, val_b, C, B, n);
  mfma_linear_kernel<128, 128, true, true><<<g_lin, blk, 0, stream>>>(
      B, nullptr, nullptr, Wb1b, bb1, D, n);                                // g1
  spmm_bf16_kernel<<<g_sp, blk, 0, stream>>>(rpb, col_b, val_b, D, B, n);   // g2
  mfma_linear_kernel<384, 128, true, true><<<g_lin, blk, 0, stream>>>(
      C, D, B, Wmb, bm, A, n);                                              // x_b

  // out = concat(x_a, x_b) @ Wo.T + bo   (fp32 out)
  mfma_linear_kernel<256, 64, false, false><<<g_lin, blk, 0, stream>>>(
      Eo, A, nullptr, Wob, bo, out, n);
}

// Round 3
// 329.733 us; speedup vs baseline: 2.0840x; 1.2647x over previous
//
#include <hip/hip_runtime.h>

// ---------------------------------------------------------------------------
// DualGCN, bf16-MFMA version, SpMM v2 (ILP-unrolled gather).
//   All [N,128] intermediate slabs stored as bf16 (ushort). GEMMs via
//   v_mfma_f32_16x16x32_bf16 with fp32 accumulation; SpMM gathers bf16 rows
//   (16 lanes/row x uint4) with x4-unrolled edge loop, fp32 accum.
// N=50000, E=800000, H=128, OUT=64.
// ---------------------------------------------------------------------------

typedef short short8 __attribute__((ext_vector_type(8)));
typedef float floatx4 __attribute__((ext_vector_type(4)));

__device__ inline unsigned short f2bf(float f) {
  unsigned u = __builtin_bit_cast(unsigned, f);
  u += 0x7fffu + ((u >> 16) & 1u);      // round-to-nearest-even
  return (unsigned short)(u >> 16);
}
__device__ inline unsigned pack2(float a, float b) {
  return (unsigned)f2bf(a) | ((unsigned)f2bf(b) << 16);
}
__device__ inline float bf_lo(unsigned w) {
  return __builtin_bit_cast(float, w << 16);
}
__device__ inline float bf_hi(unsigned w) {
  return __builtin_bit_cast(float, w & 0xffff0000u);
}

// rowptr[i] = first edge index e with row[e] >= i  (row is sorted)
__global__ __launch_bounds__(256) void build_rowptr_kernel(
    const int* __restrict__ row, int E, int n, int* __restrict__ rowptr)
{
  int i = blockIdx.x * blockDim.x + threadIdx.x;
  if (i > n) return;
  int lo = 0, hi = E;
  while (lo < hi) {
    int mid = (lo + hi) >> 1;
    if (row[mid] < i) lo = mid + 1; else hi = mid;
  }
  rowptr[i] = lo;
}

// fp32 -> bf16, 4 elements/thread
__global__ __launch_bounds__(256) void convert_x_kernel(
    const float* __restrict__ in, unsigned short* __restrict__ out, int n4)
{
  int i = blockIdx.x * 256 + threadIdx.x;
  if (i >= n4) return;
  float4 v = ((const float4*)in)[i];
  uint2 p; p.x = pack2(v.x, v.y); p.y = pack2(v.z, v.w);
  ((uint2*)out)[i] = p;
}

// all six weight matrices -> one concatenated bf16 buffer
__global__ __launch_bounds__(256) void convert_w_kernel(
    const float* __restrict__ Wa0, const float* __restrict__ Wa1,
    const float* __restrict__ Wb0, const float* __restrict__ Wb1,
    const float* __restrict__ Wm,  const float* __restrict__ Wo,
    unsigned short* __restrict__ out)
{
  int i = blockIdx.x * 256 + threadIdx.x;
  if (i >= 131072) return;
  float v;
  if      (i < 16384)  v = Wa0[i];
  else if (i < 32768)  v = Wa1[i - 16384];
  else if (i < 49152)  v = Wb0[i - 32768];
  else if (i < 65536)  v = Wb1[i - 49152];
  else if (i < 114688) v = Wm[i - 65536];
  else                 v = Wo[i - 114688];
  out[i] = f2bf(v);
}

// Y[r,:] = sum_e val[e] * X[col[e],:]   (bf16 in, fp32 accum, bf16 out)
// 16 lanes per row; lane owns 8 bf16 (16 B) of the 128-wide feature dim.
// Edge loop unrolled x4 (aligned int4/float4 col/val loads) -> 4 independent
// 16 B gathers in flight per row-group.
__global__ __launch_bounds__(256) void spmm_bf16_kernel(
    const int* __restrict__ rowptr, const int* __restrict__ col,
    const float* __restrict__ val, const unsigned short* __restrict__ X,
    unsigned short* __restrict__ Y, int n)
{
  int g = blockIdx.x * 16 + (threadIdx.x >> 4);
  int lane = threadIdx.x & 15;
  if (g >= n) return;
  int e0 = rowptr[g], e1 = rowptr[g + 1];

  float a0 = 0.f, a1 = 0.f, a2 = 0.f, a3 = 0.f;
  float a4 = 0.f, a5 = 0.f, a6 = 0.f, a7 = 0.f;
  const size_t loff = (size_t)lane * 8;

  auto accum = [&](int c, float v) {
    uint4 w = *(const uint4*)(X + (size_t)c * 128 + loff);
    a0 = fmaf(v, bf_lo(w.x), a0);
    a1 = fmaf(v, bf_hi(w.x), a1);
    a2 = fmaf(v, bf_lo(w.y), a2);
    a3 = fmaf(v, bf_hi(w.y), a3);
    a4 = fmaf(v, bf_lo(w.z), a4);
    a5 = fmaf(v, bf_hi(w.z), a5);
    a6 = fmaf(v, bf_lo(w.w), a6);
    a7 = fmaf(v, bf_hi(w.w), a7);
  };

  int e = e0;
  int epro = (e0 + 3) & ~3;              // align to 4 for vector col/val loads
  if (epro > e1) epro = e1;
  for (; e < epro; ++e) accum(col[e], val[e]);
  for (; e + 4 <= e1; e += 4) {
    int4   c4 = *(const int4*)(col + e);
    float4 v4 = *(const float4*)(val + e);
    uint4 w0 = *(const uint4*)(X + (size_t)c4.x * 128 + loff);
    uint4 w1 = *(const uint4*)(X + (size_t)c4.y * 128 + loff);
    uint4 w2 = *(const uint4*)(X + (size_t)c4.z * 128 + loff);
    uint4 w3 = *(const uint4*)(X + (size_t)c4.w * 128 + loff);
    a0 = fmaf(v4.x, bf_lo(w0.x), a0); a1 = fmaf(v4.x, bf_hi(w0.x), a1);
    a2 = fmaf(v4.x, bf_lo(w0.y), a2); a3 = fmaf(v4.x, bf_hi(w0.y), a3);
    a4 = fmaf(v4.x, bf_lo(w0.z), a4); a5 = fmaf(v4.x, bf_hi(w0.z), a5);
    a6 = fmaf(v4.x, bf_lo(w0.w), a6); a7 = fmaf(v4.x, bf_hi(w0.w), a7);
    a0 = fmaf(v4.y, bf_lo(w1.x), a0); a1 = fmaf(v4.y, bf_hi(w1.x), a1);
    a2 = fmaf(v4.y, bf_lo(w1.y), a2); a3 = fmaf(v4.y, bf_hi(w1.y), a3);
    a4 = fmaf(v4.y, bf_lo(w1.z), a4); a5 = fmaf(v4.y, bf_hi(w1.z), a5);
    a6 = fmaf(v4.y, bf_lo(w1.w), a6); a7 = fmaf(v4.y, bf_hi(w1.w), a7);
    a0 = fmaf(v4.z, bf_lo(w2.x), a0); a1 = fmaf(v4.z, bf_hi(w2.x), a1);
    a2 = fmaf(v4.z, bf_lo(w2.y), a2); a3 = fmaf(v4.z, bf_hi(w2.y), a3);
    a4 = fmaf(v4.z, bf_lo(w2.z), a4); a5 = fmaf(v4.z, bf_hi(w2.z), a5);
    a6 = fmaf(v4.z, bf_lo(w2.w), a6); a7 = fmaf(v4.z, bf_hi(w2.w), a7);
    a0 = fmaf(v4.w, bf_lo(w3.x), a0); a1 = fmaf(v4.w, bf_hi(w3.x), a1);
    a2 = fmaf(v4.w, bf_lo(w3.y), a2); a3 = fmaf(v4.w, bf_hi(w3.y), a3);
    a4 = fmaf(v4.w, bf_lo(w3.z), a4); a5 = fmaf(v4.w, bf_hi(w3.z), a5);
    a6 = fmaf(v4.w, bf_lo(w3.w), a6); a7 = fmaf(v4.w, bf_hi(w3.w), a7);
  }
  for (; e < e1; ++e) accum(col[e], val[e]);

  uint4 o;
  o.x = pack2(a0, a1); o.y = pack2(a2, a3);
  o.z = pack2(a4, a5); o.w = pack2(a6, a7);
  *(uint4*)(Y + (size_t)g * 128 + loff) = o;
}

// Y = (relu?)(X @ W.T + b), X bf16 (up to 3 slabs of 128 cols each = free
// concat), W bf16 [HOUT,K], Y bf16 or fp32.
// Block: 256 thr = 4 waves in 2x2 (wm,wn); tile 128 rows x HOUT cols.
// MFMA operand swap (a=W, b=X) -> lane's 4 acc regs are 4 consecutive output
// COLS -> packed 8B/16B stores.
template <int K, int HOUT, bool RELU, bool OUTBF>
__global__ __launch_bounds__(256, 2) void mfma_linear_kernel(
    const unsigned short* __restrict__ X0, const unsigned short* __restrict__ X1,
    const unsigned short* __restrict__ X2, const unsigned short* __restrict__ W,
    const float* __restrict__ b, void* __restrict__ Yv, int n)
{
  constexpr int LDX = 136;        // padded LDS row stride (bf16 units)
  constexpr int NT = HOUT / 32;   // n-tiles per wave
  constexpr int MT = 4;           // m-tiles per wave (64 rows)

  __shared__ unsigned short Xs[128 * LDX];
  __shared__ unsigned short Ws[HOUT * LDX];

  const int tid  = threadIdx.x;
  const int lane = tid & 63;
  const int wave = tid >> 6;
  const int wm   = wave >> 1;
  const int wn   = wave & 1;
  const int l15  = lane & 15;
  const int quad = lane >> 4;
  const int row0 = blockIdx.x * 128;

  const int c8   = (tid & 15) * 8;
  const int rloc = tid >> 4;

  floatx4 acc[MT][NT];
#pragma unroll
  for (int i = 0; i < MT; ++i)
#pragma unroll
    for (int j = 0; j < NT; ++j) acc[i][j] = (floatx4){0.f, 0.f, 0.f, 0.f};

  for (int kc = 0; kc < K; kc += 128) {
    const unsigned short* Xp = (kc == 0) ? X0 : (kc == 128) ? X1 : X2;
#pragma unroll
    for (int p = 0; p < 8; ++p) {
      int r = p * 16 + rloc;
      int gr = row0 + r;
      uint4 v = make_uint4(0u, 0u, 0u, 0u);
      if (gr < n) v = *(const uint4*)(Xp + (size_t)gr * 128 + c8);
      *(uint4*)(Xs + r * LDX + c8) = v;
    }
#pragma unroll
    for (int p = 0; p < HOUT / 16; ++p) {
      int r = p * 16 + rloc;
      uint4 v = *(const uint4*)(W + (size_t)r * K + kc + c8);
      *(uint4*)(Ws + r * LDX + c8) = v;
    }
    __syncthreads();
#pragma unroll
    for (int k0 = 0; k0 < 128; k0 += 32) {
      const int ko = k0 + quad * 8;
      short8 aW[NT], bX[MT];
#pragma unroll
      for (int j = 0; j < NT; ++j)
        aW[j] = *(const short8*)(Ws + (wn * (16 * NT) + j * 16 + l15) * LDX + ko);
#pragma unroll
      for (int i = 0; i < MT; ++i)
        bX[i] = *(const short8*)(Xs + (wm * 64 + i * 16 + l15) * LDX + ko);
#pragma unroll
      for (int i = 0; i < MT; ++i)
#pragma unroll
        for (int j = 0; j < NT; ++j)
          acc[i][j] = __builtin_amdgcn_mfma_f32_16x16x32_bf16(
              aW[j], bX[i], acc[i][j], 0, 0, 0);
    }
    __syncthreads();
  }

#pragma unroll
  for (int i = 0; i < MT; ++i) {
    int r = row0 + wm * 64 + i * 16 + l15;
    if (r >= n) continue;
#pragma unroll
    for (int j = 0; j < NT; ++j) {
      int c0 = wn * (16 * NT) + j * 16 + quad * 4;
      float4 bb = *(const float4*)(b + c0);
      float v0 = acc[i][j][0] + bb.x;
      float v1 = acc[i][j][1] + bb.y;
      float v2 = acc[i][j][2] + bb.z;
      float v3 = acc[i][j][3] + bb.w;
      if (RELU) {
        v0 = fmaxf(v0, 0.f); v1 = fmaxf(v1, 0.f);
        v2 = fmaxf(v2, 0.f); v3 = fmaxf(v3, 0.f);
      }
      if (OUTBF) {
        uint2 o; o.x = pack2(v0, v1); o.y = pack2(v2, v3);
        *(uint2*)((unsigned short*)Yv + (size_t)r * HOUT + c0) = o;
      } else {
        float4 o; o.x = v0; o.y = v1; o.z = v2; o.w = v3;
        *(float4*)((float*)Yv + (size_t)r * HOUT + c0) = o;
      }
    }
  }
}

extern "C" void kernel_launch(void* const* d_in, const int* in_sizes, int n_in,
                              void* d_out, int out_size, void* d_ws, size_t ws_size,
                              hipStream_t stream)
{
  const float* x     = (const float*)d_in[0];
  const int*   row_a = (const int*)d_in[1];
  const int*   col_a = (const int*)d_in[2];
  const float* val_a = (const float*)d_in[3];
  const int*   row_b = (const int*)d_in[4];
  const int*   col_b = (const int*)d_in[5];
  const float* val_b = (const float*)d_in[6];
  const float* Wa0 = (const float*)d_in[7];  const float* ba0 = (const float*)d_in[8];
  const float* Wa1 = (const float*)d_in[9];  const float* ba1 = (const float*)d_in[10];
  const float* Wb0 = (const float*)d_in[11]; const float* bb0 = (const float*)d_in[12];
  const float* Wb1 = (const float*)d_in[13]; const float* bb1 = (const float*)d_in[14];
  const float* Wm  = (const float*)d_in[15]; const float* bm  = (const float*)d_in[16];
  const float* Wo  = (const float*)d_in[17]; const float* bo  = (const float*)d_in[18];
  float* out = (float*)d_out;

  const int n = in_sizes[0] / 128;   // 50000
  const int E = in_sizes[1];         // 800000

  char* ws = (char*)d_ws;
  size_t off = 0;
  auto alloc = [&](size_t bytes) {
    void* p = ws + off;
    off = (off + bytes + 255) & ~(size_t)255;
    return p;
  };
  int* rpa = (int*)alloc((size_t)(n + 1) * sizeof(int));
  int* rpb = (int*)alloc((size_t)(n + 1) * sizeof(int));
  unsigned short* Wcat = (unsigned short*)alloc(131072 * sizeof(unsigned short));
  const size_t slab = (size_t)n * 128 * sizeof(unsigned short);
  unsigned short* xb = (unsigned short*)alloc(slab);
  unsigned short* A  = (unsigned short*)alloc(slab);
  unsigned short* B  = (unsigned short*)alloc(slab);
  unsigned short* C  = (unsigned short*)alloc(slab);
  unsigned short* D  = (unsigned short*)alloc(slab);
  unsigned short* Eo = (unsigned short*)alloc(slab);

  const unsigned short* Wa0b = Wcat;
  const unsigned short* Wa1b = Wcat + 16384;
  const unsigned short* Wb0b = Wcat + 32768;
  const unsigned short* Wb1b = Wcat + 49152;
  const unsigned short* Wmb  = Wcat + 65536;
  const unsigned short* Wob  = Wcat + 114688;

  dim3 blk(256);
  dim3 g_rp((n + 1 + 255) / 256);
  dim3 g_cx((n * 128 / 4 + 255) / 256);
  dim3 g_cw((131072 + 255) / 256);
  dim3 g_lin((n + 127) / 128);
  dim3 g_sp((n + 15) / 16);

  build_rowptr_kernel<<<g_rp, blk, 0, stream>>>(row_a, E, n, rpa);
  build_rowptr_kernel<<<g_rp, blk, 0, stream>>>(row_b, E, n, rpb);
  convert_x_kernel<<<g_cx, blk, 0, stream>>>(x, xb, n * 128 / 4);
  convert_w_kernel<<<g_cw, blk, 0, stream>>>(Wa0, Wa1, Wb0, Wb1, Wm, Wo, Wcat);

  // branch a
  mfma_linear_kernel<128, 128, true, true><<<g_lin, blk, 0, stream>>>(
      xb, nullptr, nullptr, Wa0b, ba0, A, n);
  spmm_bf16_kernel<<<g_sp, blk, 0, stream>>>(rpa, col_a, val_a, A, B, n);
  mfma_linear_kernel<128, 128, true, true><<<g_lin, blk, 0, stream>>>(
      B, nullptr, nullptr, Wa1b, ba1, A, n);
  spmm_bf16_kernel<<<g_sp, blk, 0, stream>>>(rpa, col_a, val_a, A, Eo, n);  // x_a

  // branch b
  mfma_linear_kernel<128, 128, true, true><<<g_lin, blk, 0, stream>>>(
      xb, nullptr, nullptr, Wb0b, bb0, C, n);                               // g0
  spmm_bf16_kernel<<<g_sp, blk, 0, stream>>>(rpb, col_b, val_b, C, B, n);
  mfma_linear_kernel<128, 128, true, true><<<g_lin, blk, 0, stream>>>(
      B, nullptr, nullptr, Wb1b, bb1, D, n);                                // g1
  spmm_bf16_kernel<<<g_sp, blk, 0, stream>>>(rpb, col_b, val_b, D, B, n);   // g2
  mfma_linear_kernel<384, 128, true, true><<<g_lin, blk, 0, stream>>>(
      C, D, B, Wmb, bm, A, n);                                              // x_b

  // out = concat(x_a, x_b) @ Wo.T + bo   (fp32 out)
  mfma_linear_kernel<256, 64, false, false><<<g_lin, blk, 0, stream>>>(
      Eo, A, nullptr, Wob, bo, out, n);
}